// Round 3
// baseline (635.602 us; speedup 1.0000x reference)
//
#include <hip/hip_runtime.h>
#include <math.h>

// Problem constants (match reference setup_inputs)
#define BN     2
#define QN     4096
#define LN     1024
#define TOPKN  128
#define PI_F   3.14159265358979323846f

// ln(12.8)/7 and ln(3.2)/7 — omegas = 10*exp(i*K), matches jnp.logspace to ~1e-7 rel
#define K_OM0  0.3642064529893673
#define K_OM1  0.1661644014008115

typedef __attribute__((ext_vector_type(8))) short  s16x8;
typedef __attribute__((ext_vector_type(4))) float  f32x4;

__device__ __forceinline__ unsigned short f2bf(float f) {
    unsigned int u = __float_as_uint(f);
    u = (u + 0x7FFFu + ((u >> 16) & 1u)) >> 16;   // RNE
    return (unsigned short)u;
}

// ---------------------------------------------------------------------------
// Kernel 0: transpose+cvt all GEMM weights to bf16 wT[n][k] (k-contiguous).
// Job table over blockIdx: out(128x256) band(128x256) mod(512x256) hv(256x256)
// kvW(256x256) queryW(64x256) qW(256x128). 32x32 LDS tiles.
// ---------------------------------------------------------------------------
__global__ __launch_bounds__(256) void transpose_all(
    const float* __restrict__ outW, const float* __restrict__ bandW,
    const float* __restrict__ modW, const float* __restrict__ hvW,
    const float* __restrict__ kvW, const float* __restrict__ queryW,
    const float* __restrict__ qW,
    unsigned short* __restrict__ outT, unsigned short* __restrict__ bandT,
    unsigned short* __restrict__ modT, unsigned short* __restrict__ hvT,
    unsigned short* __restrict__ kvT, unsigned short* __restrict__ queryT,
    unsigned short* __restrict__ qT)
{
    int bid = blockIdx.x, t = threadIdx.x;
    const float* src; unsigned short* dst; int K, N, lt;
    if      (bid < 32)  { src = outW;   dst = outT;   K = 128; N = 256; lt = bid; }
    else if (bid < 64)  { src = bandW;  dst = bandT;  K = 128; N = 256; lt = bid - 32; }
    else if (bid < 192) { src = modW;   dst = modT;   K = 512; N = 256; lt = bid - 64; }
    else if (bid < 256) { src = hvW;    dst = hvT;    K = 256; N = 256; lt = bid - 192; }
    else if (bid < 320) { src = kvW;    dst = kvT;    K = 256; N = 256; lt = bid - 256; }
    else if (bid < 336) { src = queryW; dst = queryT; K = 64;  N = 256; lt = bid - 320; }
    else                { src = qW;     dst = qT;     K = 256; N = 128; lt = bid - 336; }
    int tk = K >> 5;
    int kt = lt % tk, nt = lt / tk;
    int k0 = kt * 32, n0 = nt * 32;
    __shared__ float tile[32][33];
    int tx = t & 31, ty = t >> 5;       // 32 x 8
    #pragma unroll
    for (int r = 0; r < 4; r++)
        tile[ty + 8 * r][tx] = src[(k0 + ty + 8 * r) * N + n0 + tx];
    __syncthreads();
    #pragma unroll
    for (int r = 0; r < 4; r++)
        dst[(n0 + ty + 8 * r) * K + k0 + tx] = f2bf(tile[tx][ty + 8 * r]);
}

// ---------------------------------------------------------------------------
// Kernel 1: kvf = tokens @ kv_W via MFMA (32 rows/block, fp32 out).
// ---------------------------------------------------------------------------
__global__ __launch_bounds__(256) void kv_mfma(
    const float* __restrict__ tokens, const unsigned short* __restrict__ kvT,
    float* __restrict__ kvf)
{
    int l0 = blockIdx.x * 32;
    int t = threadIdx.x;
    __shared__ __align__(16) unsigned short tok_bf[32 * 264];
    #pragma unroll
    for (int i = 0; i < 32; i++)
        tok_bf[i * 264 + t] = f2bf(tokens[(l0 + i) * 256 + t]);
    __syncthreads();
    int w = t >> 6, lane = t & 63, quad = lane >> 4, l16 = lane & 15;
    int m0 = (w >> 1) * 16, n0 = (w & 1) * 128;
    f32x4 acc[8];
    #pragma unroll
    for (int s = 0; s < 8; s++) acc[s] = (f32x4){0.f, 0.f, 0.f, 0.f};
    #pragma unroll
    for (int kt = 0; kt < 8; kt++) {
        s16x8 a = *(const s16x8*)&tok_bf[(m0 + l16) * 264 + kt * 32 + quad * 8];
        #pragma unroll
        for (int sub = 0; sub < 8; sub++) {
            s16x8 b = *(const s16x8*)&kvT[(size_t)(n0 + sub * 16 + l16) * 256 + kt * 32 + quad * 8];
            acc[sub] = __builtin_amdgcn_mfma_f32_16x16x32_bf16(a, b, acc[sub], 0, 0, 0);
        }
    }
    #pragma unroll
    for (int sub = 0; sub < 8; sub++)
        #pragma unroll
        for (int r = 0; r < 4; r++)
            kvf[(size_t)(l0 + m0 + quad * 4 + r) * 256 + n0 + sub * 16 + l16] = acc[sub][r];
}

// ---------------------------------------------------------------------------
// Kernel 2: q pipeline via MFMA (32 queries/block).
// gamma(32x64) -> xq = relu(gamma@query_W + b) -> q = xq@q_W (4096x128).
// ---------------------------------------------------------------------------
__global__ __launch_bounds__(256) void q_mfma(
    const float* __restrict__ x, const unsigned short* __restrict__ queryT,
    const float* __restrict__ query_b, const unsigned short* __restrict__ qT,
    float* __restrict__ qall)
{
    int p0 = blockIdx.x * 32;
    int t = threadIdx.x;
    __shared__ float sh_x[128];
    __shared__ __align__(16) unsigned short gam_bf[32 * 72];
    __shared__ __align__(16) unsigned short xq_bf[32 * 264];
    if (t < 128) sh_x[t] = x[p0 * 4 + t];
    __syncthreads();
    {   // gamma: 2048 elems, 8/thread, contiguous f per thread
        int e0 = t * 8;
        int g = e0 >> 6;
        #pragma unroll
        for (int j = 0; j < 8; j++) {
            int f = (e0 + j) & 63;
            int c = f >> 4, jj = f & 15, oi = jj & 7;
            float om = (float)(10.0 * exp((double)oi * K_OM0));
            float arg = PI_F * sh_x[g * 4 + c] * om;
            gam_bf[g * 72 + f] = f2bf((jj < 8) ? sinf(arg) : cosf(arg));
        }
    }
    __syncthreads();
    int w = t >> 6, lane = t & 63, quad = lane >> 4, l16 = lane & 15;
    int m0 = (w >> 1) * 16;
    {   // stage 1: N=256, each wave: mtile + 128 cols (8 subtiles)
        int n0 = (w & 1) * 128;
        f32x4 acc[8];
        #pragma unroll
        for (int s = 0; s < 8; s++) acc[s] = (f32x4){0.f, 0.f, 0.f, 0.f};
        #pragma unroll
        for (int kt = 0; kt < 2; kt++) {
            s16x8 a = *(const s16x8*)&gam_bf[(m0 + l16) * 72 + kt * 32 + quad * 8];
            #pragma unroll
            for (int sub = 0; sub < 8; sub++) {
                s16x8 b = *(const s16x8*)&queryT[(n0 + sub * 16 + l16) * 64 + kt * 32 + quad * 8];
                acc[sub] = __builtin_amdgcn_mfma_f32_16x16x32_bf16(a, b, acc[sub], 0, 0, 0);
            }
        }
        #pragma unroll
        for (int sub = 0; sub < 8; sub++) {
            int col = n0 + sub * 16 + l16;
            float bias = query_b[col];
            #pragma unroll
            for (int r = 0; r < 4; r++)
                xq_bf[(m0 + quad * 4 + r) * 264 + col] = f2bf(fmaxf(acc[sub][r] + bias, 0.f));
        }
    }
    __syncthreads();
    {   // stage 2: N=128, wave: mtile + 64 cols
        int n0 = (w & 1) * 64;
        f32x4 acc[4];
        #pragma unroll
        for (int s = 0; s < 4; s++) acc[s] = (f32x4){0.f, 0.f, 0.f, 0.f};
        #pragma unroll
        for (int kt = 0; kt < 8; kt++) {
            s16x8 a = *(const s16x8*)&xq_bf[(m0 + l16) * 264 + kt * 32 + quad * 8];
            #pragma unroll
            for (int sub = 0; sub < 4; sub++) {
                s16x8 b = *(const s16x8*)&qT[(n0 + sub * 16 + l16) * 256 + kt * 32 + quad * 8];
                acc[sub] = __builtin_amdgcn_mfma_f32_16x16x32_bf16(a, b, acc[sub], 0, 0, 0);
            }
        }
        #pragma unroll
        for (int sub = 0; sub < 4; sub++)
            #pragma unroll
            for (int r = 0; r < 4; r++)
                qall[(size_t)(p0 + m0 + quad * 4 + r) * 128 + n0 + sub * 16 + l16] = acc[sub][r];
    }
}

// ---------------------------------------------------------------------------
// Kernel 3: fused attention (VALU, barrier-light) + MFMA MLP. G=16 q/block.
// ---------------------------------------------------------------------------
__global__ __launch_bounds__(256, 2) void attn_mlp_kernel(
    const float* __restrict__ x,
    const float* __restrict__ kvf, const float* __restrict__ qall,
    const unsigned short* __restrict__ outT, const float* __restrict__ out_b,
    const unsigned short* __restrict__ bandT, const float* __restrict__ band_b,
    const unsigned short* __restrict__ modT, const float* __restrict__ mod_b,
    const unsigned short* __restrict__ hvT, const float* __restrict__ hv_b,
    const float* __restrict__ outl_W, const float* __restrict__ outl_b,
    const int* __restrict__ gDp, const int* __restrict__ gHp,
    const int* __restrict__ gWp, const int* __restrict__ gTp,
    float* __restrict__ out)
{
    const int bid = blockIdx.x;
    const int b   = bid >> 8;                // 256 blocks per batch
    const int q0  = (bid & 255) * 16;
    const int t   = threadIdx.x;
    const int wid = t >> 6;
    const int lane = t & 63;
    const int quad = lane >> 4;
    const int l16  = lane & 15;
    const int n0   = wid * 64;

    __shared__ float q_s[2048];                         // [g][128]
    __shared__ float attn_T[16 * 256];                  // [g][h*128+kk]
    __shared__ __align__(16) unsigned short gam_bf[2 * 16 * 72];
    __shared__ __align__(16) unsigned short o_bf[16 * 136];
    __shared__ __align__(16) unsigned short modu_bf[16 * 264];
    __shared__ __align__(16) unsigned short s01_bf[16 * 264];
    __shared__ float sh_xc[64];
    __shared__ int   sh_s[16];
    __shared__ float wred[64], wred2[64];
    __shared__ float fin[64];

    // ---- stage q (coalesced), coords ----
    #pragma unroll
    for (int i = 0; i < 8; i++) q_s[i * 256 + t] = qall[(size_t)q0 * 128 + i * 256 + t];
    if (t < 64) sh_xc[t] = x[q0 * 4 + t];
    __syncthreads();

    // ---- layer gammas (bf16, A-layout rows) + window starts ----
    {
        int e0 = t * 8;
        int l = e0 >> 10, g = (e0 >> 6) & 15;
        #pragma unroll
        for (int j = 0; j < 8; j++) {
            int f = (e0 + j) & 63;
            int c = f >> 4, jj = f & 15, oi = jj & 7;
            float om = (float)(10.0 * exp((double)oi * (l ? K_OM1 : K_OM0)));
            float arg = PI_F * sh_xc[g * 4 + c] * om;
            gam_bf[(l * 16 + g) * 72 + f] = f2bf((jj < 8) ? sinf(arg) : cosf(arg));
        }
    }
    if (t < 16) {
        int gD = gDp[0], gH = gHp[0], gW = gWp[0], gT = gTp[0];
        float g0 = sh_xc[t * 4 + 0], g1 = sh_xc[t * 4 + 1];
        float g2 = sh_xc[t * 4 + 2], g3 = sh_xc[t * 4 + 3];
        int zi = (int)(g0 * (float)gD);
        int yi = (int)(g1 * (float)gH);
        int xi = (int)(g2 * (float)gW);
        int ti = (int)(g3 * (float)gT);
        int idx = ((ti * gD + zi) * gH + yi) * gW + xi;
        int Ng = gD * gH * gW * gT;
        float tt = (float)idx / (float)Ng;
        int s = (int)ceilf(tt * (float)LN - ((float)(TOPKN / 2) + 0.5f));
        sh_s[t] = min(max(s, 0), LN - TOPKN);
    }
    __syncthreads();

    // ---- sim for all 16 queries (no barriers inside) ----
    const int h  = t >> 7;
    const int kk = t & 127;
    float e16[16];
    #pragma unroll
    for (int g = 0; g < 16; g++) {
        const float* kr = kvf + (size_t)(b * LN + sh_s[g] + kk) * 256 + h * 64;
        const float* qr = q_s + g * 128 + h * 64;
        float a0 = 0.f, a1 = 0.f, a2 = 0.f, a3 = 0.f;
        #pragma unroll
        for (int d = 0; d < 4; d++) {
            float4 k0 = *(const float4*)(kr + d * 16);
            float4 k1 = *(const float4*)(kr + d * 16 + 4);
            float4 k2 = *(const float4*)(kr + d * 16 + 8);
            float4 k3 = *(const float4*)(kr + d * 16 + 12);
            a0 += qr[d*16+0]*k0.x + qr[d*16+1]*k0.y + qr[d*16+2]*k0.z + qr[d*16+3]*k0.w;
            a1 += qr[d*16+4]*k1.x + qr[d*16+5]*k1.y + qr[d*16+6]*k1.z + qr[d*16+7]*k1.w;
            a2 += qr[d*16+8]*k2.x + qr[d*16+9]*k2.y + qr[d*16+10]*k2.z + qr[d*16+11]*k2.w;
            a3 += qr[d*16+12]*k3.x + qr[d*16+13]*k3.y + qr[d*16+14]*k3.z + qr[d*16+15]*k3.w;
        }
        e16[g] = ((a0 + a1) + (a2 + a3)) * 0.125f;
    }
    // ---- softmax (all 16 queries, 3 barriers total) ----
    #pragma unroll
    for (int g = 0; g < 16; g++) {
        float m = e16[g];
        #pragma unroll
        for (int off = 1; off < 64; off <<= 1) m = fmaxf(m, __shfl_xor(m, off));
        if (lane == 0) wred[wid * 16 + g] = m;
    }
    __syncthreads();
    #pragma unroll
    for (int g = 0; g < 16; g++) {
        float mx = fmaxf(wred[(h * 2) * 16 + g], wred[(h * 2 + 1) * 16 + g]);
        float e = expf(e16[g] - mx);
        e16[g] = e;
        float ss = e;
        #pragma unroll
        for (int off = 1; off < 64; off <<= 1) ss += __shfl_xor(ss, off);
        if (lane == 0) wred2[wid * 16 + g] = ss;
    }
    __syncthreads();
    #pragma unroll
    for (int g = 0; g < 16; g++) {
        float inv = 1.f / (wred2[(h * 2) * 16 + g] + wred2[(h * 2 + 1) * 16 + g]);
        attn_T[g * 256 + t] = e16[g] * inv;
    }
    __syncthreads();

    // ---- o = attn @ V : thread = (col j, query-half), full 128-key dot ----
    {
        const int j  = t & 127;
        const int gh = t >> 7;
        const int hh = j >> 6;
        #pragma unroll
        for (int gi = 0; gi < 8; gi++) {
            int g = gh * 8 + gi;
            const float* vp = kvf + (size_t)(b * LN + sh_s[g]) * 256 + 128 + j;
            const float* ap = attn_T + g * 256 + hh * 128;
            float oa0 = 0.f, oa1 = 0.f;
            #pragma unroll 8
            for (int k2 = 0; k2 < 128; k2 += 2) {
                oa0 += ap[k2]     * vp[(size_t)k2 * 256];
                oa1 += ap[k2 + 1] * vp[(size_t)(k2 + 1) * 256];
            }
            o_bf[g * 136 + j] = f2bf(oa0 + oa1);
        }
    }
    __syncthreads();

    // ---- modulation = o @ out_W + out_b  (MFMA, K=128) ----
    {
        f32x4 acc[4];
        #pragma unroll
        for (int s = 0; s < 4; s++) acc[s] = (f32x4){0.f, 0.f, 0.f, 0.f};
        #pragma unroll
        for (int kt = 0; kt < 4; kt++) {
            s16x8 a = *(const s16x8*)&o_bf[l16 * 136 + kt * 32 + quad * 8];
            #pragma unroll
            for (int sub = 0; sub < 4; sub++) {
                s16x8 bf = *(const s16x8*)&outT[(n0 + sub * 16 + l16) * 128 + kt * 32 + quad * 8];
                acc[sub] = __builtin_amdgcn_mfma_f32_16x16x32_bf16(a, bf, acc[sub], 0, 0, 0);
            }
        }
        #pragma unroll
        for (int sub = 0; sub < 4; sub++) {
            int col = n0 + sub * 16 + l16;
            float bias = out_b[col];
            #pragma unroll
            for (int r = 0; r < 4; r++)
                modu_bf[(quad * 4 + r) * 264 + col] = f2bf(acc[sub][r] + bias);
        }
    }
    __syncthreads();

    // ---- band + mod layers (MFMA), m0 kept in regs, s01 -> LDS ----
    float m0f[16];
    #pragma unroll
    for (int l = 0; l < 2; l++) {
        f32x4 acc1[4], acc2[4];
        #pragma unroll
        for (int s = 0; s < 4; s++) { acc1[s] = (f32x4){0.f,0.f,0.f,0.f}; acc2[s] = (f32x4){0.f,0.f,0.f,0.f}; }
        #pragma unroll
        for (int kt = 0; kt < 2; kt++) {
            s16x8 a = *(const s16x8*)&gam_bf[(l * 16 + l16) * 72 + kt * 32 + quad * 8];
            #pragma unroll
            for (int sub = 0; sub < 4; sub++) {
                s16x8 bf = *(const s16x8*)&bandT[(n0 + sub * 16 + l16) * 128 + l * 64 + kt * 32 + quad * 8];
                acc1[sub] = __builtin_amdgcn_mfma_f32_16x16x32_bf16(a, bf, acc1[sub], 0, 0, 0);
            }
        }
        #pragma unroll
        for (int kt = 0; kt < 8; kt++) {
            s16x8 a = *(const s16x8*)&modu_bf[l16 * 264 + kt * 32 + quad * 8];
            #pragma unroll
            for (int sub = 0; sub < 4; sub++) {
                s16x8 bf = *(const s16x8*)&modT[(size_t)(n0 + sub * 16 + l16) * 512 + l * 256 + kt * 32 + quad * 8];
                acc2[sub] = __builtin_amdgcn_mfma_f32_16x16x32_bf16(a, bf, acc2[sub], 0, 0, 0);
            }
        }
        #pragma unroll
        for (int sub = 0; sub < 4; sub++) {
            int col = n0 + sub * 16 + l16;
            float bb = band_b[l * 256 + col];
            float mb = mod_b[l * 256 + col];
            #pragma unroll
            for (int r = 0; r < 4; r++) {
                float hval = fmaxf(acc1[sub][r] + bb, 0.f);
                float mval = fmaxf(hval + acc2[sub][r] + mb, 0.f);
                if (l == 0) m0f[sub * 4 + r] = mval;
                else s01_bf[(quad * 4 + r) * 264 + col] = f2bf(m0f[sub * 4 + r] + mval);
            }
        }
    }
    __syncthreads();

    // ---- h_v1 = relu(s01 @ hv_W + hv_b) (MFMA, K=256) + final head ----
    {
        f32x4 acc[4];
        #pragma unroll
        for (int s = 0; s < 4; s++) acc[s] = (f32x4){0.f, 0.f, 0.f, 0.f};
        #pragma unroll
        for (int kt = 0; kt < 8; kt++) {
            s16x8 a = *(const s16x8*)&s01_bf[l16 * 264 + kt * 32 + quad * 8];
            #pragma unroll
            for (int sub = 0; sub < 4; sub++) {
                s16x8 bf = *(const s16x8*)&hvT[(size_t)(n0 + sub * 16 + l16) * 256 + kt * 32 + quad * 8];
                acc[sub] = __builtin_amdgcn_mfma_f32_16x16x32_bf16(a, bf, acc[sub], 0, 0, 0);
            }
        }
        float w0s[4], w1s[4], hb[4];
        #pragma unroll
        for (int sub = 0; sub < 4; sub++) {
            int col = n0 + sub * 16 + l16;
            w0s[sub] = outl_W[col];
            w1s[sub] = outl_W[256 + col];
            hb[sub]  = hv_b[col];
        }
        #pragma unroll
        for (int r = 0; r < 4; r++) {
            float pv = 0.f;
            #pragma unroll
            for (int sub = 0; sub < 4; sub++) {
                float hvv = fmaxf(acc[sub][r] + hb[sub], 0.f);
                pv += m0f[sub * 4 + r] * w0s[sub] + hvv * w1s[sub];
            }
            #pragma unroll
            for (int off = 1; off < 16; off <<= 1) pv += __shfl_xor(pv, off);
            if (l16 == 0) fin[wid * 16 + quad * 4 + r] = pv;
        }
    }
    __syncthreads();
    if (t < 16)
        out[b * QN + q0 + t] = fin[t] + fin[16 + t] + fin[32 + t] + fin[48 + t]
                             + outl_b[0] + outl_b[1];
}

// ---------------------------------------------------------------------------
extern "C" void kernel_launch(void* const* d_in, const int* in_sizes, int n_in,
                              void* d_out, int out_size, void* d_ws, size_t ws_size,
                              hipStream_t stream)
{
    const float* x       = (const float*)d_in[0];
    const float* tokens  = (const float*)d_in[1];
    const float* query_W = (const float*)d_in[2];
    const float* query_b = (const float*)d_in[3];
    const float* q_W     = (const float*)d_in[4];
    const float* kv_W    = (const float*)d_in[5];
    const float* out_W   = (const float*)d_in[6];
    const float* out_b   = (const float*)d_in[7];
    const float* band_W  = (const float*)d_in[8];
    const float* band_b  = (const float*)d_in[9];
    const float* mod_W   = (const float*)d_in[10];
    const float* mod_b   = (const float*)d_in[11];
    const float* hv_W    = (const float*)d_in[12];
    const float* hv_b    = (const float*)d_in[13];
    const float* outl_W  = (const float*)d_in[14];
    const float* outl_b  = (const float*)d_in[15];
    const int*   gD      = (const int*)d_in[16];
    const int*   gH      = (const int*)d_in[17];
    const int*   gW      = (const int*)d_in[18];
    const int*   gT      = (const int*)d_in[19];

    float* ws   = (float*)d_ws;
    float* kvf  = ws;                          // 524288 floats
    float* qall = ws + 524288;                 // 524288 floats
    unsigned short* wb = (unsigned short*)(ws + 1048576);
    unsigned short* outT   = wb;               // 32768
    unsigned short* bandT  = wb + 32768;       // 32768
    unsigned short* modT   = wb + 65536;       // 131072
    unsigned short* hvT    = wb + 196608;      // 65536
    unsigned short* kvT    = wb + 262144;      // 65536
    unsigned short* queryT = wb + 327680;      // 16384
    unsigned short* qT     = wb + 344064;      // 32768
    float* out = (float*)d_out;

    transpose_all<<<368, 256, 0, stream>>>(out_W, band_W, mod_W, hv_W, kv_W,
                                           query_W, q_W,
                                           outT, bandT, modT, hvT, kvT, queryT, qT);
    kv_mfma<<<64, 256, 0, stream>>>(tokens, kvT, kvf);
    q_mfma<<<128, 256, 0, stream>>>(x, queryT, query_b, qT, qall);
    attn_mlp_kernel<<<512, 256, 0, stream>>>(x, kvf, qall,
        outT, out_b, bandT, band_b, modT, mod_b, hvT, hv_b,
        outl_W, outl_b, gD, gH, gW, gT, out);
}

// Round 4
// 287.776 us; speedup vs baseline: 2.2087x; 2.2087x over previous
//
#include <hip/hip_runtime.h>
#include <math.h>

// Problem constants (match reference setup_inputs)
#define BN     2
#define QN     4096
#define LN     1024
#define TOPKN  128
#define PI_F   3.14159265358979323846f

// ln(12.8)/7 and ln(3.2)/7 — omegas = 10*exp(i*K), matches jnp.logspace to ~1e-7 rel
#define K_OM0  0.3642064529893673
#define K_OM1  0.1661644014008115

typedef __attribute__((ext_vector_type(8))) short  s16x8;
typedef __attribute__((ext_vector_type(4))) float  f32x4;

__device__ __forceinline__ unsigned short f2bf(float f) {
    unsigned int u = __float_as_uint(f);
    u = (u + 0x7FFFu + ((u >> 16) & 1u)) >> 16;   // RNE
    return (unsigned short)u;
}

// ---------------------------------------------------------------------------
// Kernel 0: transpose+cvt all GEMM weights to bf16 wT[n][k] (k-contiguous).
// ---------------------------------------------------------------------------
__global__ __launch_bounds__(256) void transpose_all(
    const float* __restrict__ outW, const float* __restrict__ bandW,
    const float* __restrict__ modW, const float* __restrict__ hvW,
    const float* __restrict__ kvW, const float* __restrict__ queryW,
    const float* __restrict__ qW,
    unsigned short* __restrict__ outT, unsigned short* __restrict__ bandT,
    unsigned short* __restrict__ modT, unsigned short* __restrict__ hvT,
    unsigned short* __restrict__ kvT, unsigned short* __restrict__ queryT,
    unsigned short* __restrict__ qT)
{
    int bid = blockIdx.x, t = threadIdx.x;
    const float* src; unsigned short* dst; int K, N, lt;
    if      (bid < 32)  { src = outW;   dst = outT;   K = 128; N = 256; lt = bid; }
    else if (bid < 64)  { src = bandW;  dst = bandT;  K = 128; N = 256; lt = bid - 32; }
    else if (bid < 192) { src = modW;   dst = modT;   K = 512; N = 256; lt = bid - 64; }
    else if (bid < 256) { src = hvW;    dst = hvT;    K = 256; N = 256; lt = bid - 192; }
    else if (bid < 320) { src = kvW;    dst = kvT;    K = 256; N = 256; lt = bid - 256; }
    else if (bid < 336) { src = queryW; dst = queryT; K = 64;  N = 256; lt = bid - 320; }
    else                { src = qW;     dst = qT;     K = 256; N = 128; lt = bid - 336; }
    int tk = K >> 5;
    int kt = lt % tk, nt = lt / tk;
    int k0 = kt * 32, n0 = nt * 32;
    __shared__ float tile[32][33];
    int tx = t & 31, ty = t >> 5;       // 32 x 8
    #pragma unroll
    for (int r = 0; r < 4; r++)
        tile[ty + 8 * r][tx] = src[(k0 + ty + 8 * r) * N + n0 + tx];
    __syncthreads();
    #pragma unroll
    for (int r = 0; r < 4; r++)
        dst[(n0 + ty + 8 * r) * K + k0 + tx] = f2bf(tile[tx][ty + 8 * r]);
}

// ---------------------------------------------------------------------------
// Kernel 1: kvf = tokens @ kv_W via MFMA (32 rows/block, fp32 out).
// ---------------------------------------------------------------------------
__global__ __launch_bounds__(256) void kv_mfma(
    const float* __restrict__ tokens, const unsigned short* __restrict__ kvT,
    float* __restrict__ kvf)
{
    int l0 = blockIdx.x * 32;
    int t = threadIdx.x;
    __shared__ __align__(16) unsigned short tok_bf[32 * 264];
    #pragma unroll
    for (int i = 0; i < 32; i++)
        tok_bf[i * 264 + t] = f2bf(tokens[(l0 + i) * 256 + t]);
    __syncthreads();
    int w = t >> 6, lane = t & 63, quad = lane >> 4, l16 = lane & 15;
    int m0 = (w >> 1) * 16, n0 = (w & 1) * 128;
    f32x4 acc[8];
    #pragma unroll
    for (int s = 0; s < 8; s++) acc[s] = (f32x4){0.f, 0.f, 0.f, 0.f};
    #pragma unroll
    for (int kt = 0; kt < 8; kt++) {
        s16x8 a = *(const s16x8*)&tok_bf[(m0 + l16) * 264 + kt * 32 + quad * 8];
        #pragma unroll
        for (int sub = 0; sub < 8; sub++) {
            s16x8 b = *(const s16x8*)&kvT[(size_t)(n0 + sub * 16 + l16) * 256 + kt * 32 + quad * 8];
            acc[sub] = __builtin_amdgcn_mfma_f32_16x16x32_bf16(a, b, acc[sub], 0, 0, 0);
        }
    }
    #pragma unroll
    for (int sub = 0; sub < 8; sub++)
        #pragma unroll
        for (int r = 0; r < 4; r++)
            kvf[(size_t)(l0 + m0 + quad * 4 + r) * 256 + n0 + sub * 16 + l16] = acc[sub][r];
}

// ---------------------------------------------------------------------------
// Kernel 2: q pipeline via MFMA (32 queries/block).
// ---------------------------------------------------------------------------
__global__ __launch_bounds__(256) void q_mfma(
    const float* __restrict__ x, const unsigned short* __restrict__ queryT,
    const float* __restrict__ query_b, const unsigned short* __restrict__ qT,
    float* __restrict__ qall)
{
    int p0 = blockIdx.x * 32;
    int t = threadIdx.x;
    __shared__ float sh_x[128];
    __shared__ __align__(16) unsigned short gam_bf[32 * 72];
    __shared__ __align__(16) unsigned short xq_bf[32 * 264];
    if (t < 128) sh_x[t] = x[p0 * 4 + t];
    __syncthreads();
    {
        int e0 = t * 8;
        int g = e0 >> 6;
        #pragma unroll
        for (int j = 0; j < 8; j++) {
            int f = (e0 + j) & 63;
            int c = f >> 4, jj = f & 15, oi = jj & 7;
            float om = (float)(10.0 * exp((double)oi * K_OM0));
            float arg = PI_F * sh_x[g * 4 + c] * om;
            gam_bf[g * 72 + f] = f2bf((jj < 8) ? sinf(arg) : cosf(arg));
        }
    }
    __syncthreads();
    int w = t >> 6, lane = t & 63, quad = lane >> 4, l16 = lane & 15;
    int m0 = (w >> 1) * 16;
    {
        int n0 = (w & 1) * 128;
        f32x4 acc[8];
        #pragma unroll
        for (int s = 0; s < 8; s++) acc[s] = (f32x4){0.f, 0.f, 0.f, 0.f};
        #pragma unroll
        for (int kt = 0; kt < 2; kt++) {
            s16x8 a = *(const s16x8*)&gam_bf[(m0 + l16) * 72 + kt * 32 + quad * 8];
            #pragma unroll
            for (int sub = 0; sub < 8; sub++) {
                s16x8 b = *(const s16x8*)&queryT[(n0 + sub * 16 + l16) * 64 + kt * 32 + quad * 8];
                acc[sub] = __builtin_amdgcn_mfma_f32_16x16x32_bf16(a, b, acc[sub], 0, 0, 0);
            }
        }
        #pragma unroll
        for (int sub = 0; sub < 8; sub++) {
            int col = n0 + sub * 16 + l16;
            float bias = query_b[col];
            #pragma unroll
            for (int r = 0; r < 4; r++)
                xq_bf[(m0 + quad * 4 + r) * 264 + col] = f2bf(fmaxf(acc[sub][r] + bias, 0.f));
        }
    }
    __syncthreads();
    {
        int n0 = (w & 1) * 64;
        f32x4 acc[4];
        #pragma unroll
        for (int s = 0; s < 4; s++) acc[s] = (f32x4){0.f, 0.f, 0.f, 0.f};
        #pragma unroll
        for (int kt = 0; kt < 8; kt++) {
            s16x8 a = *(const s16x8*)&xq_bf[(m0 + l16) * 264 + kt * 32 + quad * 8];
            #pragma unroll
            for (int sub = 0; sub < 4; sub++) {
                s16x8 b = *(const s16x8*)&qT[(n0 + sub * 16 + l16) * 256 + kt * 32 + quad * 8];
                acc[sub] = __builtin_amdgcn_mfma_f32_16x16x32_bf16(a, b, acc[sub], 0, 0, 0);
            }
        }
        #pragma unroll
        for (int sub = 0; sub < 4; sub++)
            #pragma unroll
            for (int r = 0; r < 4; r++)
                qall[(size_t)(p0 + m0 + quad * 4 + r) * 128 + n0 + sub * 16 + l16] = acc[sub][r];
    }
}

// ---------------------------------------------------------------------------
// Kernel 3: layer gammas -> bf16 global, batch-independent (computed once).
// gamb[(l*4096 + q)*64 + f]. 4 threads per query row.
// ---------------------------------------------------------------------------
__global__ __launch_bounds__(256) void gamma_kernel(
    const float* __restrict__ x, unsigned short* __restrict__ gamb)
{
    int gid = blockIdx.x * 256 + threadIdx.x;  // 16384 threads
    int row = gid >> 2, sub = gid & 3;
    int l = sub >> 1, h32 = sub & 1;
    float xc0 = x[row * 4 + 0], xc1 = x[row * 4 + 1];
    float xc2 = x[row * 4 + 2], xc3 = x[row * 4 + 3];
    double kom = l ? K_OM1 : K_OM0;
    unsigned short* dst = gamb + (size_t)(l * QN + row) * 64 + h32 * 32;
    #pragma unroll
    for (int j = 0; j < 32; j++) {
        int f = h32 * 32 + j;
        int c = f >> 4, jj = f & 15, oi = jj & 7;
        float om = (float)(10.0 * exp((double)oi * kom));
        float gc = (c == 0) ? xc0 : (c == 1) ? xc1 : (c == 2) ? xc2 : xc3;
        float arg = PI_F * gc * om;
        dst[j] = f2bf((jj < 8) ? sinf(arg) : cosf(arg));
    }
}

// ---------------------------------------------------------------------------
// Kernel 4: attention (VALU). 8 queries/block, 1024 blocks.
// Wave = (head = wid&1, query-parity = wid>>1); lane holds keys {lane, lane+64}
// -> full per-head softmax with in-wave shuffles only (zero barriers in sim).
// Writes o as bf16 row-major (k-contiguous) = MFMA A-fragment-ready.
// ---------------------------------------------------------------------------
__global__ __launch_bounds__(256) void attn_kernel(
    const float* __restrict__ x,
    const float* __restrict__ kvf, const float* __restrict__ qall,
    const int* __restrict__ gDp, const int* __restrict__ gHp,
    const int* __restrict__ gWp, const int* __restrict__ gTp,
    unsigned short* __restrict__ o_bf)
{
    const int bid = blockIdx.x;
    const int b   = bid >> 9;
    const int q0  = (bid & 511) * 8;
    const int t   = threadIdx.x;
    const int wid = t >> 6;
    const int lane = t & 63;

    __shared__ __align__(16) float q_s[8 * 128];
    __shared__ __align__(16) float attn_T[8][256];
    __shared__ int sh_s[8];

    #pragma unroll
    for (int i = 0; i < 4; i++) q_s[t + 256 * i] = qall[(size_t)q0 * 128 + t + 256 * i];
    if (t < 8) {
        int gD = gDp[0], gH = gHp[0], gW = gWp[0], gT = gTp[0];
        float g0 = x[(q0 + t) * 4 + 0], g1 = x[(q0 + t) * 4 + 1];
        float g2 = x[(q0 + t) * 4 + 2], g3 = x[(q0 + t) * 4 + 3];
        int zi = (int)(g0 * (float)gD);
        int yi = (int)(g1 * (float)gH);
        int xi = (int)(g2 * (float)gW);
        int ti = (int)(g3 * (float)gT);
        int idx = ((ti * gD + zi) * gH + yi) * gW + xi;
        int Ng = gD * gH * gW * gT;
        float tt = (float)idx / (float)Ng;
        int s = (int)ceilf(tt * (float)LN - ((float)(TOPKN / 2) + 0.5f));
        sh_s[t] = min(max(s, 0), LN - TOPKN);
    }
    __syncthreads();

    // ---- sim + softmax, per-wave (head h, queries gpar+2i) ----
    const int h = wid & 1, gpar = wid >> 1;
    for (int i = 0; i < 4; i++) {
        int g = gpar + 2 * i;
        int s = sh_s[g];
        const float* k0p = kvf + (size_t)(b * LN + s + lane) * 256 + h * 64;
        const float* k1p = k0p + 64 * 256;
        const float* qp  = q_s + g * 128 + h * 64;
        float a0 = 0.f, a1 = 0.f;
        #pragma unroll
        for (int d4 = 0; d4 < 16; d4++) {
            float4 qv = *(const float4*)(qp + d4 * 4);
            float4 k0 = *(const float4*)(k0p + d4 * 4);
            float4 k1 = *(const float4*)(k1p + d4 * 4);
            a0 += qv.x * k0.x + qv.y * k0.y + qv.z * k0.z + qv.w * k0.w;
            a1 += qv.x * k1.x + qv.y * k1.y + qv.z * k1.z + qv.w * k1.w;
        }
        a0 *= 0.125f; a1 *= 0.125f;
        float m = fmaxf(a0, a1);
        #pragma unroll
        for (int off = 1; off < 64; off <<= 1) m = fmaxf(m, __shfl_xor(m, off));
        float e0 = expf(a0 - m), e1 = expf(a1 - m);
        float ss = e0 + e1;
        #pragma unroll
        for (int off = 1; off < 64; off <<= 1) ss += __shfl_xor(ss, off);
        float inv = 1.f / ss;
        attn_T[g][h * 128 + lane]      = e0 * inv;
        attn_T[g][h * 128 + 64 + lane] = e1 * inv;
    }
    __syncthreads();

    // ---- o = attn @ V : thread = (col j, query-half); 4 queries each ----
    const int j = t & 127, half = t >> 7, hh = j >> 6;
    for (int gi = 0; gi < 4; gi++) {
        int g = half * 4 + gi;
        int s = sh_s[g];
        const float* vp = kvf + (size_t)(b * LN + s) * 256 + 128 + j;
        const float* ap = &attn_T[g][hh * 128];
        float oa = 0.f;
        #pragma unroll 4
        for (int k4 = 0; k4 < 32; k4++) {
            float4 a4 = *(const float4*)(ap + k4 * 4);
            oa += a4.x * vp[(size_t)(k4 * 4 + 0) * 256]
                + a4.y * vp[(size_t)(k4 * 4 + 1) * 256]
                + a4.z * vp[(size_t)(k4 * 4 + 2) * 256]
                + a4.w * vp[(size_t)(k4 * 4 + 3) * 256];
        }
        o_bf[(size_t)(b * QN + q0 + g) * 128 + j] = f2bf(oa);
    }
}

// ---------------------------------------------------------------------------
// Kernel 5: MFMA MLP. 16 rows/block, 512 blocks. Wave = 64 output cols.
// modulation -> (band+mod) x2 -> hv -> scalar head. A-frags from global bf16
// (o_bf, gamb) or LDS (modu, s01). Register-light: no full-unroll pressure.
// ---------------------------------------------------------------------------
__global__ __launch_bounds__(256) void mlp_kernel(
    const unsigned short* __restrict__ o_bf, const unsigned short* __restrict__ gamb,
    const unsigned short* __restrict__ outT, const float* __restrict__ out_b,
    const unsigned short* __restrict__ bandT, const float* __restrict__ band_b,
    const unsigned short* __restrict__ modT, const float* __restrict__ mod_b,
    const unsigned short* __restrict__ hvT, const float* __restrict__ hv_b,
    const float* __restrict__ outl_W, const float* __restrict__ outl_b,
    float* __restrict__ out)
{
    const int r0 = blockIdx.x * 16;        // global rows (b*QN + q)
    const int t = threadIdx.x;
    const int wid = t >> 6, lane = t & 63;
    const int quad = lane >> 4, l16 = lane & 15;
    const int n0 = wid * 64;

    __shared__ __align__(16) unsigned short modu_lds[16 * 264];
    __shared__ __align__(16) unsigned short s01_lds[16 * 264];
    __shared__ float fin[64];

    // ---- modulation = o @ out_W + out_b (K=128) ----
    {
        f32x4 acc[4];
        #pragma unroll
        for (int s = 0; s < 4; s++) acc[s] = (f32x4){0.f, 0.f, 0.f, 0.f};
        #pragma unroll
        for (int kt = 0; kt < 4; kt++) {
            s16x8 a = *(const s16x8*)&o_bf[(size_t)(r0 + l16) * 128 + kt * 32 + quad * 8];
            #pragma unroll
            for (int sub = 0; sub < 4; sub++) {
                s16x8 bf = *(const s16x8*)&outT[(n0 + sub * 16 + l16) * 128 + kt * 32 + quad * 8];
                acc[sub] = __builtin_amdgcn_mfma_f32_16x16x32_bf16(a, bf, acc[sub], 0, 0, 0);
            }
        }
        #pragma unroll
        for (int sub = 0; sub < 4; sub++) {
            int col = n0 + sub * 16 + l16;
            float bias = out_b[col];
            #pragma unroll
            for (int r = 0; r < 4; r++)
                modu_lds[(quad * 4 + r) * 264 + col] = f2bf(acc[sub][r] + bias);
        }
    }
    __syncthreads();

    // ---- band + mod layers ----
    const int qrow0 = r0 & (QN - 1);
    float m0f[16];
    #pragma unroll
    for (int l = 0; l < 2; l++) {
        f32x4 acc1[4], acc2[4];
        #pragma unroll
        for (int s = 0; s < 4; s++) { acc1[s] = (f32x4){0.f,0.f,0.f,0.f}; acc2[s] = (f32x4){0.f,0.f,0.f,0.f}; }
        #pragma unroll
        for (int kt = 0; kt < 2; kt++) {
            s16x8 a = *(const s16x8*)&gamb[(size_t)(l * QN + qrow0 + l16) * 64 + kt * 32 + quad * 8];
            #pragma unroll
            for (int sub = 0; sub < 4; sub++) {
                s16x8 bf = *(const s16x8*)&bandT[(n0 + sub * 16 + l16) * 128 + l * 64 + kt * 32 + quad * 8];
                acc1[sub] = __builtin_amdgcn_mfma_f32_16x16x32_bf16(a, bf, acc1[sub], 0, 0, 0);
            }
        }
        #pragma unroll
        for (int kt = 0; kt < 8; kt++) {
            s16x8 a = *(const s16x8*)&modu_lds[l16 * 264 + kt * 32 + quad * 8];
            #pragma unroll
            for (int sub = 0; sub < 4; sub++) {
                s16x8 bf = *(const s16x8*)&modT[(size_t)(n0 + sub * 16 + l16) * 512 + l * 256 + kt * 32 + quad * 8];
                acc2[sub] = __builtin_amdgcn_mfma_f32_16x16x32_bf16(a, bf, acc2[sub], 0, 0, 0);
            }
        }
        #pragma unroll
        for (int sub = 0; sub < 4; sub++) {
            int col = n0 + sub * 16 + l16;
            float bb = band_b[l * 256 + col];
            float mb = mod_b[l * 256 + col];
            #pragma unroll
            for (int r = 0; r < 4; r++) {
                float hval = fmaxf(acc1[sub][r] + bb, 0.f);
                float mval = fmaxf(hval + acc2[sub][r] + mb, 0.f);
                if (l == 0) m0f[sub * 4 + r] = mval;
                else s01_lds[(quad * 4 + r) * 264 + col] = f2bf(m0f[sub * 4 + r] + mval);
            }
        }
    }
    __syncthreads();

    // ---- h_v1 = relu(s01 @ hv_W + hv_b) + scalar head ----
    {
        f32x4 acc[4];
        #pragma unroll
        for (int s = 0; s < 4; s++) acc[s] = (f32x4){0.f, 0.f, 0.f, 0.f};
        #pragma unroll
        for (int kt = 0; kt < 8; kt++) {
            s16x8 a = *(const s16x8*)&s01_lds[l16 * 264 + kt * 32 + quad * 8];
            #pragma unroll
            for (int sub = 0; sub < 4; sub++) {
                s16x8 bf = *(const s16x8*)&hvT[(size_t)(n0 + sub * 16 + l16) * 256 + kt * 32 + quad * 8];
                acc[sub] = __builtin_amdgcn_mfma_f32_16x16x32_bf16(a, bf, acc[sub], 0, 0, 0);
            }
        }
        float w0s[4], w1s[4], hb[4];
        #pragma unroll
        for (int sub = 0; sub < 4; sub++) {
            int col = n0 + sub * 16 + l16;
            w0s[sub] = outl_W[col];
            w1s[sub] = outl_W[256 + col];
            hb[sub]  = hv_b[col];
        }
        #pragma unroll
        for (int r = 0; r < 4; r++) {
            float pv = 0.f;
            #pragma unroll
            for (int sub = 0; sub < 4; sub++) {
                float hvv = fmaxf(acc[sub][r] + hb[sub], 0.f);
                pv += m0f[sub * 4 + r] * w0s[sub] + hvv * w1s[sub];
            }
            #pragma unroll
            for (int off = 1; off < 16; off <<= 1) pv += __shfl_xor(pv, off);
            if (l16 == 0) fin[wid * 16 + quad * 4 + r] = pv;
        }
    }
    __syncthreads();
    if (t < 16)
        out[r0 + t] = fin[t] + fin[16 + t] + fin[32 + t] + fin[48 + t]
                    + outl_b[0] + outl_b[1];
}

// ---------------------------------------------------------------------------
extern "C" void kernel_launch(void* const* d_in, const int* in_sizes, int n_in,
                              void* d_out, int out_size, void* d_ws, size_t ws_size,
                              hipStream_t stream)
{
    const float* x       = (const float*)d_in[0];
    const float* tokens  = (const float*)d_in[1];
    const float* query_W = (const float*)d_in[2];
    const float* query_b = (const float*)d_in[3];
    const float* q_W     = (const float*)d_in[4];
    const float* kv_W    = (const float*)d_in[5];
    const float* out_W   = (const float*)d_in[6];
    const float* out_b   = (const float*)d_in[7];
    const float* band_W  = (const float*)d_in[8];
    const float* band_b  = (const float*)d_in[9];
    const float* mod_W   = (const float*)d_in[10];
    const float* mod_b   = (const float*)d_in[11];
    const float* hv_W    = (const float*)d_in[12];
    const float* hv_b    = (const float*)d_in[13];
    const float* outl_W  = (const float*)d_in[14];
    const float* outl_b  = (const float*)d_in[15];
    const int*   gD      = (const int*)d_in[16];
    const int*   gH      = (const int*)d_in[17];
    const int*   gW      = (const int*)d_in[18];
    const int*   gT      = (const int*)d_in[19];

    float* ws   = (float*)d_ws;
    float* kvf  = ws;                          // 524288 floats
    float* qall = ws + 524288;                 // 524288 floats
    unsigned short* wb = (unsigned short*)(ws + 1048576);
    unsigned short* outT   = wb;               // 32768
    unsigned short* bandT  = wb + 32768;       // 32768
    unsigned short* modT   = wb + 65536;       // 131072
    unsigned short* hvT    = wb + 196608;      // 65536
    unsigned short* kvT    = wb + 262144;      // 65536
    unsigned short* queryT = wb + 327680;      // 16384
    unsigned short* qT     = wb + 344064;      // 32768
    unsigned short* o_bf   = wb + 376832;      // 8192*128 = 1048576
    unsigned short* gamb   = wb + 1425408;     // 2*4096*64 = 524288
    float* out = (float*)d_out;

    transpose_all<<<368, 256, 0, stream>>>(out_W, band_W, mod_W, hv_W, kv_W,
                                           query_W, q_W,
                                           outT, bandT, modT, hvT, kvT, queryT, qT);
    gamma_kernel<<<64, 256, 0, stream>>>(x, gamb);
    kv_mfma<<<64, 256, 0, stream>>>(tokens, kvT, kvf);
    q_mfma<<<128, 256, 0, stream>>>(x, queryT, query_b, qT, qall);
    attn_kernel<<<1024, 256, 0, stream>>>(x, kvf, qall, gD, gH, gW, gT, o_bf);
    mlp_kernel<<<512, 256, 0, stream>>>(o_bf, gamb,
        outT, out_b, bandT, band_b, modT, mod_b, hvT, hv_b,
        outl_W, outl_b, out);
}